// Round 1
// 153.411 us; speedup vs baseline: 1.0137x; 1.0137x over previous
//
#include <hip/hip_runtime.h>

// ROI bilinear crop+resize, round 3: compile-time POOL specialization.
//
// Unchanged (carried from round 2b, all verified):
//   - block = one (roi, py) output row: 256 threads = 128 ch-float4 x 2 px-subsets
//   - XCD-clustered blockIdx remap (rows of one ROI share an XCD's L2)
//   - nontemporal float4 output stores (streaming, zero reuse)
//
// New: POOL is a template parameter (pool==14 fast path). The px loop had a
// runtime trip count, so the compiler could not unroll it: each iteration was
// 4 gathers + a dependent FMA chain = ~7 serialized cache-latency batches.
// Now: phase 1 computes all per-px x offsets (pure VALU, no memory), phase 2
// is a fully unrolled gather+blend+store loop -> scheduler can hoist loads
// across iterations and keep up to 28 global_load_dwordx4 in flight per wave.
// Arithmetic is bit-identical to round 2b (same op order, true divides).

typedef float vfloat4 __attribute__((ext_vector_type(4)));

__device__ __forceinline__ int remap_block(int bid, int nblk) {
    // XCD-clustered remap (bijective when nblk % 8 == 0; 3584 % 8 == 0)
    if ((nblk & 7) == 0) {
        const int per_xcd = nblk >> 3;
        return (bid & 7) * per_xcd + (bid >> 3);
    }
    return bid;
}

template <int POOL>
__global__ __launch_bounds__(256)
void roi_bilinear_row_fixed(const float* __restrict__ img,
                            const int*   __restrict__ rois,
                            float*       __restrict__ out,
                            int W, int nroi) {
    const int C4 = 128;                    // 512 channels / 4 floats
    const int lin = remap_block(blockIdx.x, nroi * POOL);
    const int roi = lin / POOL;
    const int py  = lin - roi * POOL;

    const int4 rv = reinterpret_cast<const int4*>(rois)[roi]; // x, y, w, h
    const float poolf = (float)POOL;

    // y axis (offset rv.y, size rv.w == h)
    const float hf = (float)rv.w;
    float sy = ((float)py + 0.5f) * (hf / poolf) - 0.5f;  // true div, like ref
    sy = fminf(fmaxf(sy, 0.0f), hf - 1.0f);               // clip BEFORE floor
    const int   i0y = (int)sy;                            // sy >= 0: trunc == floor
    const int   i1y = min(i0y + 1, rv.w - 1);
    const float fy  = sy - (float)i0y;
    const int   y0  = rv.y + i0y;
    const int   y1  = rv.y + i1y;
    const float gy  = 1.0f - fy;

    // x axis common factors (offset rv.x, size rv.z == w)
    const float wf = (float)rv.z;
    const float xscale = wf / poolf;
    const float xmax = wf - 1.0f;
    const int   xlim = rv.z - 1;

    const int c4  = threadIdx.x & (C4 - 1);
    const int sub = threadIdx.x >> 7;      // 0 or 1

    const vfloat4* __restrict__ imgv = reinterpret_cast<const vfloat4*>(img);
    vfloat4* __restrict__ outv = reinterpret_cast<vfloat4*>(out);

    const size_t row0 = (size_t)(y0 * W) * C4 + c4;
    const size_t row1 = (size_t)(y1 * W) * C4 + c4;
    const size_t outbase = (size_t)lin * POOL * C4 + c4;

    constexpr int NPX = POOL / 2;          // px per thread (POOL even)

    // Phase 1: all per-px x coordinates (no memory ops; statically indexed
    // arrays -> registers after full unroll)
    int   xo0[NPX], xo1[NPX];
    float fxa[NPX];
#pragma unroll
    for (int k = 0; k < NPX; ++k) {
        const int px = 2 * k + sub;
        float sx = ((float)px + 0.5f) * xscale - 0.5f;
        sx = fminf(fmaxf(sx, 0.0f), xmax);
        const int i0x = (int)sx;           // sx >= 0: trunc == floor
        fxa[k] = sx - (float)i0x;
        xo0[k] = (rv.x + i0x) * C4;
        xo1[k] = (rv.x + min(i0x + 1, xlim)) * C4;
    }

    // Phase 2: fully unrolled gather + blend + store. Iterations are
    // independent; scheduler can issue loads many iterations ahead.
#pragma unroll
    for (int k = 0; k < NPX; ++k) {
        const vfloat4 v00 = imgv[row0 + xo0[k]];
        const vfloat4 v01 = imgv[row0 + xo1[k]];
        const vfloat4 v10 = imgv[row1 + xo0[k]];
        const vfloat4 v11 = imgv[row1 + xo1[k]];

        const float fx = fxa[k];
        const float gx = 1.0f - fx;
        vfloat4 o = (v00 * gx + v01 * fx) * gy + (v10 * gx + v11 * fx) * fy;

        __builtin_nontemporal_store(o, &outv[outbase + (size_t)(2 * k + sub) * C4]);
    }
}

// Generic fallback (identical to round 2b) for pool != 14.
__global__ __launch_bounds__(256)
void roi_bilinear_row_generic(const float* __restrict__ img,
                              const int*   __restrict__ rois,
                              float*       __restrict__ out,
                              int W, int pool, int nroi) {
    const int C4 = 128;
    const int lin = remap_block(blockIdx.x, nroi * pool);
    const int roi = lin / pool;
    const int py  = lin - roi * pool;

    const int4 rv = reinterpret_cast<const int4*>(rois)[roi];
    const float poolf = (float)pool;

    const float hf = (float)rv.w;
    float sy = ((float)py + 0.5f) * (hf / poolf) - 0.5f;
    sy = fminf(fmaxf(sy, 0.0f), hf - 1.0f);
    const int   i0y = (int)floorf(sy);
    const int   i1y = min(i0y + 1, rv.w - 1);
    const float fy  = sy - (float)i0y;
    const int   y0  = rv.y + i0y;
    const int   y1  = rv.y + i1y;
    const float gy  = 1.0f - fy;

    const float wf = (float)rv.z;
    const float xscale = wf / poolf;
    const float xmax = wf - 1.0f;
    const int   xlim = rv.z - 1;

    const int c4  = threadIdx.x & (C4 - 1);
    const int sub = threadIdx.x >> 7;

    const vfloat4* __restrict__ imgv = reinterpret_cast<const vfloat4*>(img);
    vfloat4* __restrict__ outv = reinterpret_cast<vfloat4*>(out);

    const size_t row0 = (size_t)(y0 * W) * C4 + c4;
    const size_t row1 = (size_t)(y1 * W) * C4 + c4;
    const size_t outbase = (size_t)lin * pool * C4 + c4;

    for (int px = sub; px < pool; px += 2) {
        float sx = ((float)px + 0.5f) * xscale - 0.5f;
        sx = fminf(fmaxf(sx, 0.0f), xmax);
        const int   i0x = (int)floorf(sx);
        const int   i1x = min(i0x + 1, xlim);
        const float fx  = sx - (float)i0x;
        const int   x0  = (rv.x + i0x) * C4;
        const int   x1  = (rv.x + i1x) * C4;

        const vfloat4 v00 = imgv[row0 + x0];
        const vfloat4 v01 = imgv[row0 + x1];
        const vfloat4 v10 = imgv[row1 + x0];
        const vfloat4 v11 = imgv[row1 + x1];

        const float gx = 1.0f - fx;
        vfloat4 o = (v00 * gx + v01 * fx) * gy + (v10 * gx + v11 * fx) * fy;

        __builtin_nontemporal_store(o, &outv[outbase + (size_t)px * C4]);
    }
}

extern "C" void kernel_launch(void* const* d_in, const int* in_sizes, int n_in,
                              void* d_out, int out_size, void* d_ws, size_t ws_size,
                              hipStream_t stream) {
    const float* img  = (const float*)d_in[0];   // [1,128,128,512] f32
    const int*   rois = (const int*)d_in[1];     // [1,256,4] i32
    float* out = (float*)d_out;

    const int W = 128, C = 512;
    const int num_rois = in_sizes[1] / 4;        // 256

    // out_size = num_rois * pool^2 * C  ->  pool = isqrt(out_size/(num_rois*C))
    const int pp = out_size / (num_rois * C);    // pool^2
    int pool = 1;
    while ((pool + 1) * (pool + 1) <= pp) ++pool;

    const int nblk = num_rois * pool;            // 3584 blocks (256 thr each)
    if (pool == 14) {
        roi_bilinear_row_fixed<14><<<nblk, 256, 0, stream>>>(img, rois, out,
                                                             W, num_rois);
    } else {
        roi_bilinear_row_generic<<<nblk, 256, 0, stream>>>(img, rois, out,
                                                           W, pool, num_rois);
    }
}